// Round 5
// baseline (12490.964 us; speedup 1.0000x reference)
//
#include <hip/hip_runtime.h>

typedef float v2f __attribute__((ext_vector_type(2)));

// Problem dims
#define B_Q 128
#define T_Q 1024
#define I_Q 256
#define H_Q 512

// Partition: 8 groups x 16 batches; 64 slices/group x 8 h-cols; 512 WGs x 256 thr.
// RESIDENCY LAW (rounds 0/1/3): achieved waves/SIMD == 2nd launch_bounds arg;
// arg=2 -> 2 WGs/CU -> 512 slots -> grid MUST be 512 WGs (fully resident).
// PAIRED-XCD MAPPING (round-4 post-mortem): wg%8 = XCD, r = wg>>3 = dispatch
// slot within XCD; CU c hosts slots c and c+32. Round 4 (g = wg&7) made both
// co-resident WGs the SAME group -> lockstep spins, VALUBusy 44%->23%. Here
// groups (2p,2p+1) pair with XCDs (2p,2p+1): slots 0..31 carry one group of
// the pair, slots 32..63 the other -> each CU hosts BOTH paired groups
// (stall overlap, round-0 style) while each group stays within 2 XCDs
// (L2-local x/hbuf/counter traffic, round-4 style). Pure bijection ->
// correctness mapping-independent.
#define NGR    8
#define BG     16
#define JW     8
#define NWG    512
#define NTHR   256
#define WPG    (NWG / NGR)               // 64 WGs per group
#define C1     (B_Q * 4 * H_Q)           // copy-1 offset in out (262144 floats)

// LDS: h tile chunked: 16 rows x 64 chunks x (8 floats + 2 pad), + transpose buf
#define CH_STR  10
#define ROW_STR 640                      // 64 * 10 (multiple of 32 -> bank pattern row-invariant)
#define HT_FLOATS (BG * ROW_STR)         // 10240
#define TB_FLOATS (BG * 9)               // 144 (stride 9: conflict-free transpose)
#define LDS_FLOATS (HT_FLOATS + TB_FLOATS)
#define LDS_BYTES  (LDS_FLOATS * 4)      // 41536 B -> LDS allows 3 WGs/CU; law sets 2

// ---- cross-lane partner fetch, compile-time ctrl (DPP for 1,2,8; swizzle 4,16)
template<int M>
__device__ __forceinline__ float partner(float t) {
    if constexpr (M == 16)
        return __int_as_float(__builtin_amdgcn_ds_swizzle(__float_as_int(t), 0x401F));
    else if constexpr (M == 8)
        return __int_as_float(__builtin_amdgcn_update_dpp(0, __float_as_int(t), 0x128, 0xF, 0xF, true)); // row_ror:8 = xor8
    else if constexpr (M == 4)
        return __int_as_float(__builtin_amdgcn_ds_swizzle(__float_as_int(t), 0x101F));
    else if constexpr (M == 2)
        return __int_as_float(__builtin_amdgcn_update_dpp(0, __float_as_int(t), 0x4E, 0xF, 0xF, true));  // quad_perm [2,3,0,1]
    else
        return __int_as_float(__builtin_amdgcn_update_dpp(0, __float_as_int(t), 0xB1, 0xF, 0xF, true));  // quad_perm [1,0,3,2]
}

// XOR-slot butterfly, 16 slots: slot i of lane kg holds batch (i ^ (kg&15)).
// Every stage is uniformly v[i] += partner<M>(v[i+M]) -- zero cndmask selects:
// partner kg^M slot i+M holds batch (i+M)^((kg^M)&15) = i^(kg&15) (i<M).
// Scatter (8,4,2,1) first, then the symmetric ^16 fold on the single survivor.
// After: EVERY lane kg has v[0] = full 32-lane sum for batch (kg & 15).
__device__ __forceinline__ void bfly16(float* v) {
    #pragma unroll
    for (int i = 0; i < 8; ++i) v[i] += partner<8>(v[i + 8]);
    #pragma unroll
    for (int i = 0; i < 4; ++i) v[i] += partner<4>(v[i + 4]);
    v[0] += partner<2>(v[2]);
    v[1] += partner<2>(v[3]);
    v[0] += partner<1>(v[1]);
    v[0] += partner<16>(v[0]);    // symmetric fold: same (kg&15) on both sides
}

// fast gates: v_exp_f32 (base-2) + v_rcp_f32; saturating tails are exact (+-1 / 0,1)
__device__ __forceinline__ float fsig(float x) {
    return __builtin_amdgcn_rcpf(1.f + __builtin_amdgcn_exp2f(-1.44269504088896f * x));
}
__device__ __forceinline__ float ftanh(float x) {
    return 1.f - 2.f * __builtin_amdgcn_rcpf(1.f + __builtin_amdgcn_exp2f(2.88539008177793f * x));
}

extern "C" __global__ void __launch_bounds__(NTHR, 2)
__attribute__((amdgpu_num_vgpr(128)))   // fail-safe: spill beats residency loss
gru_scan_kernel(const float* __restrict__ x,
                const float* __restrict__ h0,
                const float* __restrict__ Wih,
                const float* __restrict__ bih,
                const float* __restrict__ Whh,
                const float* __restrict__ bhh,
                float* __restrict__ out,
                int* __restrict__ flags)   // d_ws: NGR arrival counters, memset-0 by host
{
    extern __shared__ float lds[];
    float* Ht   = lds;                 // [BG][ROW_STR] chunked h(t-1)
    float* tbuf = lds + HT_FLOATS;     // [BG][9] publish transpose

    const int wg  = blockIdx.x;
    const int xcd = wg & 7;               // XCD id (round-robin dispatch)
    const int r   = wg >> 3;              // dispatch slot within XCD 0..63
    const int p   = xcd >> 1;             // XCD pair 0..3
    const int g   = 2 * p + ((xcd & 1) ^ (r >> 5));  // paired-group mapping
    const int s   = r;                    // slice 0..63
    const int tid = threadIdx.x;
    const int j   = tid >> 5;             // 0..7 local col
    const int kg  = tid & 31;             // 0..31 k-group
    const int jg  = s * JW + j;           // global h-col
    const int c15 = kg & 15;              // XOR-slot key == b_own

    // Per-group hbuf scratch inside the group's OWN copy-1 output region:
    // out[C1 + g*32768 .. +16384). Only group g touches it; group g's own
    // epilogue (after its done-spin) is the only clobber -> occupancy-safe.
    float* hbuf = out + C1 + (size_t)g * (BG * 4 * H_Q);   // 2 parity x [BG][H_Q]

    // ---- W slices into registers (v2f for packed fp32 fma)
    v2f wh[3][8];   // hh: k in [8kg,8kg+8) U [256+8kg, 256+8kg+8)
    v2f wi[3][4];   // ih: k in [8kg,8kg+8)
    #pragma unroll
    for (int gt = 0; gt < 3; ++gt) {
        const float* wr = Whh + (size_t)(gt * H_Q + jg) * H_Q + 8 * kg;
        float4 t0 = *(const float4*)(wr);
        float4 t1 = *(const float4*)(wr + 4);
        float4 t2 = *(const float4*)(wr + 256);
        float4 t3 = *(const float4*)(wr + 260);
        wh[gt][0] = (v2f){t0.x, t0.y}; wh[gt][1] = (v2f){t0.z, t0.w};
        wh[gt][2] = (v2f){t1.x, t1.y}; wh[gt][3] = (v2f){t1.z, t1.w};
        wh[gt][4] = (v2f){t2.x, t2.y}; wh[gt][5] = (v2f){t2.z, t2.w};
        wh[gt][6] = (v2f){t3.x, t3.y}; wh[gt][7] = (v2f){t3.z, t3.w};
        const float* wx = Wih + (size_t)(gt * H_Q + jg) * I_Q + 8 * kg;
        float4 u0 = *(const float4*)(wx);
        float4 u1 = *(const float4*)(wx + 4);
        wi[gt][0] = (v2f){u0.x, u0.y}; wi[gt][1] = (v2f){u0.z, u0.w};
        wi[gt][2] = (v2f){u1.x, u1.y}; wi[gt][3] = (v2f){u1.z, u1.w};
    }

    const float br = bih[jg]           + bhh[jg];
    const float bz = bih[H_Q + jg]     + bhh[H_Q + jg];
    const float bin = bih[2 * H_Q + jg], bhn = bhh[2 * H_Q + jg];

    const size_t xstr_b = (size_t)T_Q * I_Q;
    const float* xbase  = x + (size_t)(g * BG) * xstr_b + 8 * kg;

    float lr = 0.f, lz = 0.f, ln = 0.f, lh = 0.f;

    for (int t = 1; t <= T_Q; ++t) {
        // ---- phase 1: x partials (independent of h(t-1) -> issues before spin)
        // slot i <-> batch (i ^ c15)  [XOR layout for the select-free butterfly]
        float pr[BG], pz[BG], pn[BG];
        const float* xt = xbase + (size_t)(t - 1) * I_Q;
        #pragma unroll
        for (int i = 0; i < BG; ++i) {
            const float* xp = xt + (size_t)(i ^ c15) * xstr_b;
            float4 xa4 = *(const float4*)(xp);
            float4 xb4 = *(const float4*)(xp + 4);
            v2f x0 = (v2f){xa4.x, xa4.y}, x1 = (v2f){xa4.z, xa4.w};
            v2f x2 = (v2f){xb4.x, xb4.y}, x3 = (v2f){xb4.z, xb4.w};
            v2f sr = x0 * wi[0][0] + x1 * wi[0][1] + x2 * wi[0][2] + x3 * wi[0][3];
            v2f sz = x0 * wi[1][0] + x1 * wi[1][1] + x2 * wi[1][2] + x3 * wi[1][3];
            v2f sn = x0 * wi[2][0] + x1 * wi[2][1] + x2 * wi[2][2] + x3 * wi[2][3];
            pr[i] = sr.x + sr.y;
            pz[i] = sz.x + sz.y;
            pn[i] = sn.x + sn.y;
        }
        bfly16(pr); bfly16(pz); bfly16(pn);
        const float oxr = pr[0], oxz = pz[0], oxn = pn[0];

        // ---- acquire h(t-1) into LDS (contiguous global -> chunked LDS)
        if (t == 1) {
            const unsigned long long* src =
                (const unsigned long long*)(h0 + (size_t)(g * BG) * H_Q);
            #pragma unroll
            for (int i = 0; i < BG; ++i) {
                int q = tid + i * NTHR;            // 0..4095
                int b = q >> 8, qr = q & 255;
                unsigned long long v = src[q];
                *(unsigned long long*)(Ht + b * ROW_STR + (qr >> 2) * CH_STR
                                       + ((qr & 3) << 1)) = v;
            }
        } else {
            // monotone arrival counter: flags[g] == WPG*(t-1) <=> all 64 WGs
            // of this group have published step t-1 (induction: a WG can only
            // publish step s after the counter reached WPG*(s-1)).
            if (tid == 0) {
                int cnt = 0;
                while (__hip_atomic_load(flags + g, __ATOMIC_RELAXED,
                                         __HIP_MEMORY_SCOPE_AGENT) < WPG * (t - 1)) {
                    __builtin_amdgcn_s_sleep(1);
                    if (++cnt > 100000000) break;   // hang guard
                }
            }
            __syncthreads();
            const unsigned long long* src = (const unsigned long long*)
                (hbuf + (size_t)((t - 1) & 1) * (BG * H_Q));
            #pragma unroll
            for (int i = 0; i < BG; ++i) {
                int q = tid + i * NTHR;
                int b = q >> 8, qr = q & 255;
                unsigned long long v = __hip_atomic_load(src + q, __ATOMIC_RELAXED,
                                                         __HIP_MEMORY_SCOPE_AGENT);
                *(unsigned long long*)(Ht + b * ROW_STR + (qr >> 2) * CH_STR
                                       + ((qr & 3) << 1)) = v;
            }
        }
        __syncthreads();

        // ---- phase 2: h partials (row i ^ c15; ROW_STR is a multiple of 32
        // so the XOR row index leaves the bank pattern unchanged)
        #pragma unroll
        for (int i = 0; i < BG; ++i) {
            const float* hp = Ht + (i ^ c15) * ROW_STR + CH_STR * kg;
            v2f a0 = *(const v2f*)(hp);
            v2f a1 = *(const v2f*)(hp + 2);
            v2f a2 = *(const v2f*)(hp + 4);
            v2f a3 = *(const v2f*)(hp + 6);
            const float* hq = hp + 32 * CH_STR;   // chunk kg+32: k = 256+8kg
            v2f c0 = *(const v2f*)(hq);
            v2f c1 = *(const v2f*)(hq + 2);
            v2f c2 = *(const v2f*)(hq + 4);
            v2f c3 = *(const v2f*)(hq + 6);
            v2f sr = a0 * wh[0][0] + a1 * wh[0][1] + a2 * wh[0][2] + a3 * wh[0][3]
                   + c0 * wh[0][4] + c1 * wh[0][5] + c2 * wh[0][6] + c3 * wh[0][7];
            v2f sz = a0 * wh[1][0] + a1 * wh[1][1] + a2 * wh[1][2] + a3 * wh[1][3]
                   + c0 * wh[1][4] + c1 * wh[1][5] + c2 * wh[1][6] + c3 * wh[1][7];
            v2f sn = a0 * wh[2][0] + a1 * wh[2][1] + a2 * wh[2][2] + a3 * wh[2][3]
                   + c0 * wh[2][4] + c1 * wh[2][5] + c2 * wh[2][6] + c3 * wh[2][7];
            pr[i] = sr.x + sr.y;
            pz[i] = sz.x + sz.y;
            pn[i] = sn.x + sn.y;
        }
        bfly16(pr); bfly16(pz); bfly16(pn);

        // previous h for this thread's (b_own = c15, col jg)
        float hx = Ht[c15 * ROW_STR + (jg >> 3) * CH_STR + (jg & 7)];

        float rg = fsig(oxr + pr[0] + br);
        float zg = fsig(oxz + pz[0] + bz);
        float ng = ftanh(oxn + bin + rg * (pn[0] + bhn));
        float hn = (1.f - zg) * ng + zg * hx;

        // ---- publish: transpose through LDS, then contiguous stores by wave 0
        // only (2 items/lane). Store + vmcnt(0) + counter-add all inside wave 0
        // (vmcnt is per-wave, counts ALL the wave's outstanding vmem ops), so
        // no trailing __syncthreads; next iteration's acquire barrier orders
        // the rest.
        if (kg < 16) tbuf[kg * 9 + j] = hn;   // kg == batch for kg<16
        __syncthreads();
        if (tid < 64) {
            float* dst = hbuf + (size_t)(t & 1) * (BG * H_Q);
            #pragma unroll
            for (int u = 0; u < 2; ++u) {
                int q = tid + u * 64;             // 0..127
                int b = q >> 3, jl = q & 7;
                __hip_atomic_store(dst + b * H_Q + s * JW + jl, tbuf[b * 9 + jl],
                                   __ATOMIC_RELAXED, __HIP_MEMORY_SCOPE_AGENT);
            }
            asm volatile("s_waitcnt vmcnt(0)" ::: "memory");
            if (tid == 0)
                __hip_atomic_fetch_add(flags + g, 1, __ATOMIC_RELAXED,
                                       __HIP_MEMORY_SCOPE_AGENT);
        }

        lr = rg; lz = zg; ln = ng; lh = hn;
    }

    // ---- per-group done: this group's counter hit WPG*T -> all 64 WGs
    // published step T, hence all hbuf reads finished. Epilogue then
    // overwrites (only) this group's own regions, including its hbuf.
    if (tid == 0) {
        int cnt = 0;
        while (__hip_atomic_load(flags + g, __ATOMIC_RELAXED,
                                 __HIP_MEMORY_SCOPE_AGENT) < WPG * T_Q) {
            __builtin_amdgcn_s_sleep(2);
            if (++cnt > 100000000) break;   // hang guard
        }
    }
    __syncthreads();

    if (kg < 16) {
        size_t o = (size_t)(g * BG + kg) * (4 * H_Q);
        out[o + jg]             = lr;
        out[o + H_Q + jg]       = lz;
        out[o + 2 * H_Q + jg]   = ln;
        out[o + 3 * H_Q + jg]   = lh;
        size_t o2 = o + (size_t)C1;
        out[o2 + jg]            = lr;
        out[o2 + H_Q + jg]      = lz;
        out[o2 + 2 * H_Q + jg]  = ln;
        out[o2 + 3 * H_Q + jg]  = lh;
    }
}

extern "C" void kernel_launch(void* const* d_in, const int* in_sizes, int n_in,
                              void* d_out, int out_size, void* d_ws, size_t ws_size,
                              hipStream_t stream) {
    const float* x   = (const float*)d_in[0];
    const float* h0  = (const float*)d_in[1];
    const float* Wih = (const float*)d_in[2];
    const float* bih = (const float*)d_in[3];
    const float* Whh = (const float*)d_in[4];
    const float* bhh = (const float*)d_in[5];
    float* outp  = (float*)d_out;
    int*   flags = (int*)d_ws;   // NGR arrival counters (32 B)

    (void)in_sizes; (void)n_in; (void)ws_size; (void)out_size;

    // zero the arrival counters every launch (stream-ordered, capture-safe)
    hipMemsetAsync(d_ws, 0, NGR * sizeof(int), stream);

    gru_scan_kernel<<<dim3(NWG), dim3(NTHR), LDS_BYTES, stream>>>(
        x, h0, Wih, bih, Whh, bhh, outp, flags);
}

// Round 6
// 11425.375 us; speedup vs baseline: 1.0933x; 1.0933x over previous
//
#include <hip/hip_runtime.h>

typedef float v2f __attribute__((ext_vector_type(2)));

// Problem dims
#define B_Q 128
#define T_Q 1024
#define I_Q 256
#define H_Q 512

// Partition: 8 groups x 16 batches; 64 slices/group x 8 h-cols; 512 WGs x 256 thr.
// RESIDENCY LAW (rounds 0/1/3): achieved waves/SIMD == 2nd launch_bounds arg;
// arg=2 -> 2 WGs/CU -> 512 slots -> grid MUST be 512 WGs (fully resident).
// MAPPING: g = wg>>6 (round-0's, the only one measured at 44% VALUBusy).
// SYNC (round-5 post-mortem): single-counter atomic_fetch_add (r4/r5) serializes
// 64 same-line RMWs at one L2 atomic unit (+~4us/step stall vs round 0, seen in
// BOTH r4 and r5 -> mapping-independent). Restored here: per-WG flag STORES
// (no RMW, independent lines pipelined) + 64-thread parallel poll (pure loads).
// Correctness is PER-GROUP only (G16): per-group flags, per-group retirement;
// hbuf scratch in the group's OWN copy-1 output region -> occupancy-safe.
#define NGR    8
#define BG     16
#define JW     8
#define NWG    512
#define NTHR   256
#define WPG    (NWG / NGR)               // 64 WGs per group
#define C1     (B_Q * 4 * H_Q)           // copy-1 offset in out (262144 floats)

// LDS: h tile chunked: 16 rows x 64 chunks x (8 floats + 2 pad), + transpose buf
#define CH_STR  10
#define ROW_STR 640                      // 64 * 10 (multiple of 32 -> bank pattern row-invariant)
#define HT_FLOATS (BG * ROW_STR)         // 10240
#define TB_FLOATS (BG * 9)               // 144 (stride 9: conflict-free transpose)
#define LDS_FLOATS (HT_FLOATS + TB_FLOATS)
#define LDS_BYTES  (LDS_FLOATS * 4)      // 41536 B -> LDS allows 3 WGs/CU; law sets 2

// ---- cross-lane partner fetch, compile-time ctrl (DPP for 1,2,8; swizzle 4,16)
template<int M>
__device__ __forceinline__ float partner(float t) {
    if constexpr (M == 16)
        return __int_as_float(__builtin_amdgcn_ds_swizzle(__float_as_int(t), 0x401F));
    else if constexpr (M == 8)
        return __int_as_float(__builtin_amdgcn_update_dpp(0, __float_as_int(t), 0x128, 0xF, 0xF, true)); // row_ror:8 = xor8
    else if constexpr (M == 4)
        return __int_as_float(__builtin_amdgcn_ds_swizzle(__float_as_int(t), 0x101F));
    else if constexpr (M == 2)
        return __int_as_float(__builtin_amdgcn_update_dpp(0, __float_as_int(t), 0x4E, 0xF, 0xF, true));  // quad_perm [2,3,0,1]
    else
        return __int_as_float(__builtin_amdgcn_update_dpp(0, __float_as_int(t), 0xB1, 0xF, 0xF, true));  // quad_perm [1,0,3,2]
}

// XOR-slot butterfly, 16 slots: slot i of lane kg holds batch (i ^ (kg&15)).
// Every stage is uniformly v[i] += partner<M>(v[i+M]) -- zero cndmask selects:
// partner kg^M slot i+M holds batch (i+M)^((kg^M)&15) = i^(kg&15) (i<M).
// Scatter (8,4,2,1) first, then the symmetric ^16 fold on the single survivor.
// After: EVERY lane kg has v[0] = full 32-lane sum for batch (kg & 15).
__device__ __forceinline__ void bfly16(float* v) {
    #pragma unroll
    for (int i = 0; i < 8; ++i) v[i] += partner<8>(v[i + 8]);
    #pragma unroll
    for (int i = 0; i < 4; ++i) v[i] += partner<4>(v[i + 4]);
    v[0] += partner<2>(v[2]);
    v[1] += partner<2>(v[3]);
    v[0] += partner<1>(v[1]);
    v[0] += partner<16>(v[0]);    // symmetric fold: same (kg&15) on both sides
}

// fast gates: v_exp_f32 (base-2) + v_rcp_f32; saturating tails are exact (+-1 / 0,1)
__device__ __forceinline__ float fsig(float x) {
    return __builtin_amdgcn_rcpf(1.f + __builtin_amdgcn_exp2f(-1.44269504088896f * x));
}
__device__ __forceinline__ float ftanh(float x) {
    return 1.f - 2.f * __builtin_amdgcn_rcpf(1.f + __builtin_amdgcn_exp2f(2.88539008177793f * x));
}

extern "C" __global__ void __launch_bounds__(NTHR, 2)
__attribute__((amdgpu_num_vgpr(128)))   // fail-safe: spill beats residency loss
gru_scan_kernel(const float* __restrict__ x,
                const float* __restrict__ h0,
                const float* __restrict__ Wih,
                const float* __restrict__ bih,
                const float* __restrict__ Whh,
                const float* __restrict__ bhh,
                float* __restrict__ out,
                int* __restrict__ flags)   // d_ws: NWG per-WG flags, memset-0 by host
{
    extern __shared__ float lds[];
    float* Ht   = lds;                 // [BG][ROW_STR] chunked h(t-1)
    float* tbuf = lds + HT_FLOATS;     // [BG][9] publish transpose

    const int wg  = blockIdx.x;
    const int g   = wg >> 6;              // group 0..7 (round-0 mapping)
    const int s   = wg & 63;              // slice 0..63
    const int tid = threadIdx.x;
    const int j   = tid >> 5;             // 0..7 local col
    const int kg  = tid & 31;             // 0..31 k-group
    const int jg  = s * JW + j;           // global h-col
    const int c15 = kg & 15;              // XOR-slot key == b_own

    // Per-group hbuf scratch inside the group's OWN copy-1 output region:
    // out[C1 + g*32768 .. +16384). Only group g touches it; group g's own
    // epilogue (after its done-spin) is the only clobber -> occupancy-safe.
    float* hbuf = out + C1 + (size_t)g * (BG * 4 * H_Q);   // 2 parity x [BG][H_Q]
    int*   gflags = flags + g * WPG;      // this group's 64 per-WG flags

    // ---- W slices into registers (v2f for packed fp32 fma)
    v2f wh[3][8];   // hh: k in [8kg,8kg+8) U [256+8kg, 256+8kg+8)
    v2f wi[3][4];   // ih: k in [8kg,8kg+8)
    #pragma unroll
    for (int gt = 0; gt < 3; ++gt) {
        const float* wr = Whh + (size_t)(gt * H_Q + jg) * H_Q + 8 * kg;
        float4 t0 = *(const float4*)(wr);
        float4 t1 = *(const float4*)(wr + 4);
        float4 t2 = *(const float4*)(wr + 256);
        float4 t3 = *(const float4*)(wr + 260);
        wh[gt][0] = (v2f){t0.x, t0.y}; wh[gt][1] = (v2f){t0.z, t0.w};
        wh[gt][2] = (v2f){t1.x, t1.y}; wh[gt][3] = (v2f){t1.z, t1.w};
        wh[gt][4] = (v2f){t2.x, t2.y}; wh[gt][5] = (v2f){t2.z, t2.w};
        wh[gt][6] = (v2f){t3.x, t3.y}; wh[gt][7] = (v2f){t3.z, t3.w};
        const float* wx = Wih + (size_t)(gt * H_Q + jg) * I_Q + 8 * kg;
        float4 u0 = *(const float4*)(wx);
        float4 u1 = *(const float4*)(wx + 4);
        wi[gt][0] = (v2f){u0.x, u0.y}; wi[gt][1] = (v2f){u0.z, u0.w};
        wi[gt][2] = (v2f){u1.x, u1.y}; wi[gt][3] = (v2f){u1.z, u1.w};
    }

    const float br = bih[jg]           + bhh[jg];
    const float bz = bih[H_Q + jg]     + bhh[H_Q + jg];
    const float bin = bih[2 * H_Q + jg], bhn = bhh[2 * H_Q + jg];

    const size_t xstr_b = (size_t)T_Q * I_Q;
    const float* xbase  = x + (size_t)(g * BG) * xstr_b + 8 * kg;

    float lr = 0.f, lz = 0.f, ln = 0.f, lh = 0.f;

    for (int t = 1; t <= T_Q; ++t) {
        // ---- phase 1: x partials (independent of h(t-1) -> issues before spin)
        // slot i <-> batch (i ^ c15)  [XOR layout for the select-free butterfly]
        float pr[BG], pz[BG], pn[BG];
        const float* xt = xbase + (size_t)(t - 1) * I_Q;
        #pragma unroll
        for (int i = 0; i < BG; ++i) {
            const float* xp = xt + (size_t)(i ^ c15) * xstr_b;
            float4 xa4 = *(const float4*)(xp);
            float4 xb4 = *(const float4*)(xp + 4);
            v2f x0 = (v2f){xa4.x, xa4.y}, x1 = (v2f){xa4.z, xa4.w};
            v2f x2 = (v2f){xb4.x, xb4.y}, x3 = (v2f){xb4.z, xb4.w};
            v2f sr = x0 * wi[0][0] + x1 * wi[0][1] + x2 * wi[0][2] + x3 * wi[0][3];
            v2f sz = x0 * wi[1][0] + x1 * wi[1][1] + x2 * wi[1][2] + x3 * wi[1][3];
            v2f sn = x0 * wi[2][0] + x1 * wi[2][1] + x2 * wi[2][2] + x3 * wi[2][3];
            pr[i] = sr.x + sr.y;
            pz[i] = sz.x + sz.y;
            pn[i] = sn.x + sn.y;
        }
        bfly16(pr); bfly16(pz); bfly16(pn);
        const float oxr = pr[0], oxz = pz[0], oxn = pn[0];

        // ---- acquire h(t-1) into LDS (contiguous global -> chunked LDS)
        if (t == 1) {
            const unsigned long long* src =
                (const unsigned long long*)(h0 + (size_t)(g * BG) * H_Q);
            #pragma unroll
            for (int i = 0; i < BG; ++i) {
                int q = tid + i * NTHR;            // 0..4095
                int b = q >> 8, qr = q & 255;
                unsigned long long v = src[q];
                *(unsigned long long*)(Ht + b * ROW_STR + (qr >> 2) * CH_STR
                                       + ((qr & 3) << 1)) = v;
            }
        } else {
            // 64 threads poll 64 per-WG flags IN PARALLEL (pure loads, no RMW
            // anywhere): thread u exits when WG u of this group published t-1.
            if (tid < WPG) {
                int cnt = 0;
                while (__hip_atomic_load(gflags + tid, __ATOMIC_RELAXED,
                                         __HIP_MEMORY_SCOPE_AGENT) < t - 1) {
                    __builtin_amdgcn_s_sleep(1);
                    if (++cnt > 100000000) break;   // hang guard
                }
            }
            __syncthreads();
            const unsigned long long* src = (const unsigned long long*)
                (hbuf + (size_t)((t - 1) & 1) * (BG * H_Q));
            #pragma unroll
            for (int i = 0; i < BG; ++i) {
                int q = tid + i * NTHR;
                int b = q >> 8, qr = q & 255;
                unsigned long long v = __hip_atomic_load(src + q, __ATOMIC_RELAXED,
                                                         __HIP_MEMORY_SCOPE_AGENT);
                *(unsigned long long*)(Ht + b * ROW_STR + (qr >> 2) * CH_STR
                                       + ((qr & 3) << 1)) = v;
            }
        }
        __syncthreads();

        // ---- phase 2: h partials (row i ^ c15; ROW_STR is a multiple of 32
        // so the XOR row index leaves the bank pattern unchanged)
        #pragma unroll
        for (int i = 0; i < BG; ++i) {
            const float* hp = Ht + (i ^ c15) * ROW_STR + CH_STR * kg;
            v2f a0 = *(const v2f*)(hp);
            v2f a1 = *(const v2f*)(hp + 2);
            v2f a2 = *(const v2f*)(hp + 4);
            v2f a3 = *(const v2f*)(hp + 6);
            const float* hq = hp + 32 * CH_STR;   // chunk kg+32: k = 256+8kg
            v2f c0 = *(const v2f*)(hq);
            v2f c1 = *(const v2f*)(hq + 2);
            v2f c2 = *(const v2f*)(hq + 4);
            v2f c3 = *(const v2f*)(hq + 6);
            v2f sr = a0 * wh[0][0] + a1 * wh[0][1] + a2 * wh[0][2] + a3 * wh[0][3]
                   + c0 * wh[0][4] + c1 * wh[0][5] + c2 * wh[0][6] + c3 * wh[0][7];
            v2f sz = a0 * wh[1][0] + a1 * wh[1][1] + a2 * wh[1][2] + a3 * wh[1][3]
                   + c0 * wh[1][4] + c1 * wh[1][5] + c2 * wh[1][6] + c3 * wh[1][7];
            v2f sn = a0 * wh[2][0] + a1 * wh[2][1] + a2 * wh[2][2] + a3 * wh[2][3]
                   + c0 * wh[2][4] + c1 * wh[2][5] + c2 * wh[2][6] + c3 * wh[2][7];
            pr[i] = sr.x + sr.y;
            pz[i] = sz.x + sz.y;
            pn[i] = sn.x + sn.y;
        }
        bfly16(pr); bfly16(pz); bfly16(pn);

        // previous h for this thread's (b_own = c15, col jg)
        float hx = Ht[c15 * ROW_STR + (jg >> 3) * CH_STR + (jg & 7)];

        float rg = fsig(oxr + pr[0] + br);
        float zg = fsig(oxz + pz[0] + bz);
        float ng = ftanh(oxn + bin + rg * (pn[0] + bhn));
        float hn = (1.f - zg) * ng + zg * hx;

        // ---- publish: transpose through LDS, then contiguous stores by wave 0
        // only (2 items/lane). Store + vmcnt(0) + per-WG flag STORE (no RMW)
        // all inside wave 0 (vmcnt is per-wave, counts the wave's outstanding
        // vmem ops) -> no trailing __syncthreads; next iteration's acquire
        // barrier orders the rest.
        if (kg < 16) tbuf[kg * 9 + j] = hn;   // kg == batch for kg<16
        __syncthreads();
        if (tid < 64) {
            float* dst = hbuf + (size_t)(t & 1) * (BG * H_Q);
            #pragma unroll
            for (int u = 0; u < 2; ++u) {
                int q = tid + u * 64;             // 0..127
                int b = q >> 3, jl = q & 7;
                __hip_atomic_store(dst + b * H_Q + s * JW + jl, tbuf[b * 9 + jl],
                                   __ATOMIC_RELAXED, __HIP_MEMORY_SCOPE_AGENT);
            }
            asm volatile("s_waitcnt vmcnt(0)" ::: "memory");
            if (tid == 0)
                __hip_atomic_store(gflags + s, t, __ATOMIC_RELAXED,
                                   __HIP_MEMORY_SCOPE_AGENT);
        }

        lr = rg; lz = zg; ln = ng; lh = hn;
    }

    // ---- per-group done: all 64 of this group's flags hit T -> all WGs
    // published step T, hence all hbuf reads finished. Epilogue then
    // overwrites (only) this group's own regions, including its hbuf.
    if (tid < WPG) {
        int cnt = 0;
        while (__hip_atomic_load(gflags + tid, __ATOMIC_RELAXED,
                                 __HIP_MEMORY_SCOPE_AGENT) < T_Q) {
            __builtin_amdgcn_s_sleep(2);
            if (++cnt > 100000000) break;   // hang guard
        }
    }
    __syncthreads();

    if (kg < 16) {
        size_t o = (size_t)(g * BG + kg) * (4 * H_Q);
        out[o + jg]             = lr;
        out[o + H_Q + jg]       = lz;
        out[o + 2 * H_Q + jg]   = ln;
        out[o + 3 * H_Q + jg]   = lh;
        size_t o2 = o + (size_t)C1;
        out[o2 + jg]            = lr;
        out[o2 + H_Q + jg]      = lz;
        out[o2 + 2 * H_Q + jg]  = ln;
        out[o2 + 3 * H_Q + jg]  = lh;
    }
}

extern "C" void kernel_launch(void* const* d_in, const int* in_sizes, int n_in,
                              void* d_out, int out_size, void* d_ws, size_t ws_size,
                              hipStream_t stream) {
    const float* x   = (const float*)d_in[0];
    const float* h0  = (const float*)d_in[1];
    const float* Wih = (const float*)d_in[2];
    const float* bih = (const float*)d_in[3];
    const float* Whh = (const float*)d_in[4];
    const float* bhh = (const float*)d_in[5];
    float* outp  = (float*)d_out;
    int*   flags = (int*)d_ws;   // NWG per-WG step flags (2 KB)

    (void)in_sizes; (void)n_in; (void)ws_size; (void)out_size;

    // zero the per-WG flags every launch (stream-ordered, capture-safe)
    hipMemsetAsync(d_ws, 0, NWG * sizeof(int), stream);

    gru_scan_kernel<<<dim3(NWG), dim3(NTHR), LDS_BYTES, stream>>>(
        x, h0, Wih, bih, Whh, bhh, outp, flags);
}

// Round 7
// 9419.002 us; speedup vs baseline: 1.3261x; 1.2130x over previous
//
#include <hip/hip_runtime.h>

typedef float v2f __attribute__((ext_vector_type(2)));

// Problem dims
#define B_Q 128
#define T_Q 1024
#define I_Q 256
#define H_Q 512

// Partition: 8 groups x 16 batches; 64 slices/group x 8 h-cols; 512 WGs x 256 thr.
// RESIDENCY LAW (rounds 0/1/3): achieved waves/SIMD == 2nd launch_bounds arg;
// arg=2 -> 2 WGs/CU -> 512 slots -> grid MUST be 512 WGs (fully resident).
// SYNC (r6, proven): per-WG flag STORES (no RMW) + 64-thread parallel poll.
// X-ACCESS (r7 fix): phase-1 global x loads are LINEAR in batch (slot i =
// batch i) -> each load instr covers ~1KB contiguous (8 lines) instead of the
// r6 XOR-scatter's 16 rows x 4KB apart (~32 lines/instr, ~4x TA work,
// +2.5us/step stall -- the measured r0->r6 stall regression). The select-free
// XOR butterfly is kept ONLY for phase 2, where the scatter lives in LDS and
// is bank-invariant (ROW_STR % 32 == 0) -> free.
// Correctness is PER-GROUP only (G16): per-group flags, per-group retirement;
// hbuf scratch in the group's OWN copy-1 output region -> occupancy-safe.
#define NGR    8
#define BG     16
#define JW     8
#define NWG    512
#define NTHR   256
#define WPG    (NWG / NGR)               // 64 WGs per group
#define C1     (B_Q * 4 * H_Q)           // copy-1 offset in out (262144 floats)

// LDS: h tile chunked: 16 rows x 64 chunks x (8 floats + 2 pad), + transpose buf
#define CH_STR  10
#define ROW_STR 640                      // 64 * 10 (multiple of 32 -> bank pattern row-invariant)
#define HT_FLOATS (BG * ROW_STR)         // 10240
#define TB_FLOATS (BG * 9)               // 144 (stride 9: conflict-free transpose)
#define LDS_FLOATS (HT_FLOATS + TB_FLOATS)
#define LDS_BYTES  (LDS_FLOATS * 4)      // 41536 B -> LDS allows 3 WGs/CU; law sets 2

// ---- cross-lane partner fetch, compile-time ctrl (DPP for 1,2,8; swizzle 4,16)
template<int M>
__device__ __forceinline__ float partner(float t) {
    if constexpr (M == 16)
        return __int_as_float(__builtin_amdgcn_ds_swizzle(__float_as_int(t), 0x401F));
    else if constexpr (M == 8)
        return __int_as_float(__builtin_amdgcn_update_dpp(0, __float_as_int(t), 0x128, 0xF, 0xF, true)); // row_ror:8 = xor8
    else if constexpr (M == 4)
        return __int_as_float(__builtin_amdgcn_ds_swizzle(__float_as_int(t), 0x101F));
    else if constexpr (M == 2)
        return __int_as_float(__builtin_amdgcn_update_dpp(0, __float_as_int(t), 0x4E, 0xF, 0xF, true));  // quad_perm [2,3,0,1]
    else
        return __int_as_float(__builtin_amdgcn_update_dpp(0, __float_as_int(t), 0xB1, 0xF, 0xF, true));  // quad_perm [1,0,3,2]
}

// ---- phase-1 butterfly (linear slots, round-0 proven): fold ^16 symmetric,
// then reduce-scatter ^8..^1 with keep/send selects. After: EVERY lane kg has
// v[0] = full 32-lane sum for batch (kg & 15).
template<int M, int N>
__device__ __forceinline__ void bstage(float* v, bool hi) {
    #pragma unroll
    for (int i = 0; i < N / 2; ++i) {
        float keep = hi ? v[i + N / 2] : v[i];
        float send = hi ? v[i]         : v[i + N / 2];
        v[i] = keep + partner<M>(send);
    }
}
__device__ __forceinline__ void bflychunk(float* v, int kg) {
    #pragma unroll
    for (int i = 0; i < 16; ++i) v[i] += partner<16>(v[i]);
    bstage<8, 16>(v, (kg & 8) != 0);
    bstage<4, 8 >(v, (kg & 4) != 0);
    bstage<2, 4 >(v, (kg & 2) != 0);
    bstage<1, 2 >(v, (kg & 1) != 0);
}

// ---- phase-2 butterfly (XOR slots, select-free): slot i of lane kg holds
// batch (i ^ (kg&15)); every stage is uniformly v[i] += partner<M>(v[i+M])
// (partner kg^M slot i+M holds batch (i+M)^((kg^M)&15) = i^(kg&15), i<M).
// After: EVERY lane kg has v[0] = full 32-lane sum for batch (kg & 15).
__device__ __forceinline__ void bfly16(float* v) {
    #pragma unroll
    for (int i = 0; i < 8; ++i) v[i] += partner<8>(v[i + 8]);
    #pragma unroll
    for (int i = 0; i < 4; ++i) v[i] += partner<4>(v[i + 4]);
    v[0] += partner<2>(v[2]);
    v[1] += partner<2>(v[3]);
    v[0] += partner<1>(v[1]);
    v[0] += partner<16>(v[0]);    // symmetric fold: same (kg&15) on both sides
}

// fast gates: v_exp_f32 (base-2) + v_rcp_f32; saturating tails are exact (+-1 / 0,1)
__device__ __forceinline__ float fsig(float x) {
    return __builtin_amdgcn_rcpf(1.f + __builtin_amdgcn_exp2f(-1.44269504088896f * x));
}
__device__ __forceinline__ float ftanh(float x) {
    return 1.f - 2.f * __builtin_amdgcn_rcpf(1.f + __builtin_amdgcn_exp2f(2.88539008177793f * x));
}

extern "C" __global__ void __launch_bounds__(NTHR, 2)
__attribute__((amdgpu_num_vgpr(128)))   // fail-safe: spill beats residency loss
gru_scan_kernel(const float* __restrict__ x,
                const float* __restrict__ h0,
                const float* __restrict__ Wih,
                const float* __restrict__ bih,
                const float* __restrict__ Whh,
                const float* __restrict__ bhh,
                float* __restrict__ out,
                int* __restrict__ flags)   // d_ws: NWG per-WG flags, memset-0 by host
{
    extern __shared__ float lds[];
    float* Ht   = lds;                 // [BG][ROW_STR] chunked h(t-1)
    float* tbuf = lds + HT_FLOATS;     // [BG][9] publish transpose

    const int wg  = blockIdx.x;
    const int g   = wg >> 6;              // group 0..7 (round-0 mapping)
    const int s   = wg & 63;              // slice 0..63
    const int tid = threadIdx.x;
    const int j   = tid >> 5;             // 0..7 local col
    const int kg  = tid & 31;             // 0..31 k-group
    const int jg  = s * JW + j;           // global h-col
    const int c15 = kg & 15;              // b_own (both butterflies land here)

    // Per-group hbuf scratch inside the group's OWN copy-1 output region:
    // out[C1 + g*32768 .. +16384). Only group g touches it; group g's own
    // epilogue (after its done-spin) is the only clobber -> occupancy-safe.
    float* hbuf = out + C1 + (size_t)g * (BG * 4 * H_Q);   // 2 parity x [BG][H_Q]
    int*   gflags = flags + g * WPG;      // this group's 64 per-WG flags

    // ---- W slices into registers (v2f for packed fp32 fma)
    v2f wh[3][8];   // hh: k in [8kg,8kg+8) U [256+8kg, 256+8kg+8)
    v2f wi[3][4];   // ih: k in [8kg,8kg+8)
    #pragma unroll
    for (int gt = 0; gt < 3; ++gt) {
        const float* wr = Whh + (size_t)(gt * H_Q + jg) * H_Q + 8 * kg;
        float4 t0 = *(const float4*)(wr);
        float4 t1 = *(const float4*)(wr + 4);
        float4 t2 = *(const float4*)(wr + 256);
        float4 t3 = *(const float4*)(wr + 260);
        wh[gt][0] = (v2f){t0.x, t0.y}; wh[gt][1] = (v2f){t0.z, t0.w};
        wh[gt][2] = (v2f){t1.x, t1.y}; wh[gt][3] = (v2f){t1.z, t1.w};
        wh[gt][4] = (v2f){t2.x, t2.y}; wh[gt][5] = (v2f){t2.z, t2.w};
        wh[gt][6] = (v2f){t3.x, t3.y}; wh[gt][7] = (v2f){t3.z, t3.w};
        const float* wx = Wih + (size_t)(gt * H_Q + jg) * I_Q + 8 * kg;
        float4 u0 = *(const float4*)(wx);
        float4 u1 = *(const float4*)(wx + 4);
        wi[gt][0] = (v2f){u0.x, u0.y}; wi[gt][1] = (v2f){u0.z, u0.w};
        wi[gt][2] = (v2f){u1.x, u1.y}; wi[gt][3] = (v2f){u1.z, u1.w};
    }

    const float br = bih[jg]           + bhh[jg];
    const float bz = bih[H_Q + jg]     + bhh[H_Q + jg];
    const float bin = bih[2 * H_Q + jg], bhn = bhh[2 * H_Q + jg];

    const size_t xstr_b = (size_t)T_Q * I_Q;
    const float* xbase  = x + (size_t)(g * BG) * xstr_b + 8 * kg;

    float lr = 0.f, lz = 0.f, ln = 0.f, lh = 0.f;

    for (int t = 1; t <= T_Q; ++t) {
        // ---- phase 1: x partials, LINEAR slots (slot i = batch i) -> each
        // load instruction is row-contiguous across lanes (coalesced).
        float pr[BG], pz[BG], pn[BG];
        const float* xt = xbase + (size_t)(t - 1) * I_Q;
        #pragma unroll
        for (int i = 0; i < BG; ++i) {
            const float* xp = xt + (size_t)i * xstr_b;
            float4 xa4 = *(const float4*)(xp);
            float4 xb4 = *(const float4*)(xp + 4);
            v2f x0 = (v2f){xa4.x, xa4.y}, x1 = (v2f){xa4.z, xa4.w};
            v2f x2 = (v2f){xb4.x, xb4.y}, x3 = (v2f){xb4.z, xb4.w};
            v2f sr = x0 * wi[0][0] + x1 * wi[0][1] + x2 * wi[0][2] + x3 * wi[0][3];
            v2f sz = x0 * wi[1][0] + x1 * wi[1][1] + x2 * wi[1][2] + x3 * wi[1][3];
            v2f sn = x0 * wi[2][0] + x1 * wi[2][1] + x2 * wi[2][2] + x3 * wi[2][3];
            pr[i] = sr.x + sr.y;
            pz[i] = sz.x + sz.y;
            pn[i] = sn.x + sn.y;
        }
        bflychunk(pr, kg); bflychunk(pz, kg); bflychunk(pn, kg);
        const float oxr = pr[0], oxz = pz[0], oxn = pn[0];

        // ---- acquire h(t-1) into LDS (contiguous global -> chunked LDS)
        if (t == 1) {
            const unsigned long long* src =
                (const unsigned long long*)(h0 + (size_t)(g * BG) * H_Q);
            #pragma unroll
            for (int i = 0; i < BG; ++i) {
                int q = tid + i * NTHR;            // 0..4095
                int b = q >> 8, qr = q & 255;
                unsigned long long v = src[q];
                *(unsigned long long*)(Ht + b * ROW_STR + (qr >> 2) * CH_STR
                                       + ((qr & 3) << 1)) = v;
            }
        } else {
            // 64 threads poll 64 per-WG flags IN PARALLEL (pure loads, no RMW
            // anywhere): thread u exits when WG u of this group published t-1.
            if (tid < WPG) {
                int cnt = 0;
                while (__hip_atomic_load(gflags + tid, __ATOMIC_RELAXED,
                                         __HIP_MEMORY_SCOPE_AGENT) < t - 1) {
                    __builtin_amdgcn_s_sleep(1);
                    if (++cnt > 100000000) break;   // hang guard
                }
            }
            __syncthreads();
            const unsigned long long* src = (const unsigned long long*)
                (hbuf + (size_t)((t - 1) & 1) * (BG * H_Q));
            #pragma unroll
            for (int i = 0; i < BG; ++i) {
                int q = tid + i * NTHR;
                int b = q >> 8, qr = q & 255;
                unsigned long long v = __hip_atomic_load(src + q, __ATOMIC_RELAXED,
                                                         __HIP_MEMORY_SCOPE_AGENT);
                *(unsigned long long*)(Ht + b * ROW_STR + (qr >> 2) * CH_STR
                                       + ((qr & 3) << 1)) = v;
            }
        }
        __syncthreads();

        // ---- phase 2: h partials, XOR slots (row i ^ c15 in LDS; ROW_STR is
        // a multiple of 32 so the XOR row leaves the bank pattern unchanged ->
        // scatter is free here, unlike global)
        #pragma unroll
        for (int i = 0; i < BG; ++i) {
            const float* hp = Ht + (i ^ c15) * ROW_STR + CH_STR * kg;
            v2f a0 = *(const v2f*)(hp);
            v2f a1 = *(const v2f*)(hp + 2);
            v2f a2 = *(const v2f*)(hp + 4);
            v2f a3 = *(const v2f*)(hp + 6);
            const float* hq = hp + 32 * CH_STR;   // chunk kg+32: k = 256+8kg
            v2f c0 = *(const v2f*)(hq);
            v2f c1 = *(const v2f*)(hq + 2);
            v2f c2 = *(const v2f*)(hq + 4);
            v2f c3 = *(const v2f*)(hq + 6);
            v2f sr = a0 * wh[0][0] + a1 * wh[0][1] + a2 * wh[0][2] + a3 * wh[0][3]
                   + c0 * wh[0][4] + c1 * wh[0][5] + c2 * wh[0][6] + c3 * wh[0][7];
            v2f sz = a0 * wh[1][0] + a1 * wh[1][1] + a2 * wh[1][2] + a3 * wh[1][3]
                   + c0 * wh[1][4] + c1 * wh[1][5] + c2 * wh[1][6] + c3 * wh[1][7];
            v2f sn = a0 * wh[2][0] + a1 * wh[2][1] + a2 * wh[2][2] + a3 * wh[2][3]
                   + c0 * wh[2][4] + c1 * wh[2][5] + c2 * wh[2][6] + c3 * wh[2][7];
            pr[i] = sr.x + sr.y;
            pz[i] = sz.x + sz.y;
            pn[i] = sn.x + sn.y;
        }
        bfly16(pr); bfly16(pz); bfly16(pn);

        // previous h for this thread's (b_own = c15, col jg)
        float hx = Ht[c15 * ROW_STR + (jg >> 3) * CH_STR + (jg & 7)];

        float rg = fsig(oxr + pr[0] + br);
        float zg = fsig(oxz + pz[0] + bz);
        float ng = ftanh(oxn + bin + rg * (pn[0] + bhn));
        float hn = (1.f - zg) * ng + zg * hx;

        // ---- publish: transpose through LDS, then contiguous stores by wave 0
        // only (2 items/lane). Store + vmcnt(0) + per-WG flag STORE (no RMW)
        // all inside wave 0 (vmcnt is per-wave) -> no trailing __syncthreads;
        // next iteration's acquire barrier orders the rest.
        if (kg < 16) tbuf[kg * 9 + j] = hn;   // kg == batch for kg<16
        __syncthreads();
        if (tid < 64) {
            float* dst = hbuf + (size_t)(t & 1) * (BG * H_Q);
            #pragma unroll
            for (int u = 0; u < 2; ++u) {
                int q = tid + u * 64;             // 0..127
                int b = q >> 3, jl = q & 7;
                __hip_atomic_store(dst + b * H_Q + s * JW + jl, tbuf[b * 9 + jl],
                                   __ATOMIC_RELAXED, __HIP_MEMORY_SCOPE_AGENT);
            }
            asm volatile("s_waitcnt vmcnt(0)" ::: "memory");
            if (tid == 0)
                __hip_atomic_store(gflags + s, t, __ATOMIC_RELAXED,
                                   __HIP_MEMORY_SCOPE_AGENT);
        }

        lr = rg; lz = zg; ln = ng; lh = hn;
    }

    // ---- per-group done: all 64 of this group's flags hit T -> all WGs
    // published step T, hence all hbuf reads finished. Epilogue then
    // overwrites (only) this group's own regions, including its hbuf.
    if (tid < WPG) {
        int cnt = 0;
        while (__hip_atomic_load(gflags + tid, __ATOMIC_RELAXED,
                                 __HIP_MEMORY_SCOPE_AGENT) < T_Q) {
            __builtin_amdgcn_s_sleep(2);
            if (++cnt > 100000000) break;   // hang guard
        }
    }
    __syncthreads();

    if (kg < 16) {
        size_t o = (size_t)(g * BG + kg) * (4 * H_Q);
        out[o + jg]             = lr;
        out[o + H_Q + jg]       = lz;
        out[o + 2 * H_Q + jg]   = ln;
        out[o + 3 * H_Q + jg]   = lh;
        size_t o2 = o + (size_t)C1;
        out[o2 + jg]            = lr;
        out[o2 + H_Q + jg]      = lz;
        out[o2 + 2 * H_Q + jg]  = ln;
        out[o2 + 3 * H_Q + jg]  = lh;
    }
}

extern "C" void kernel_launch(void* const* d_in, const int* in_sizes, int n_in,
                              void* d_out, int out_size, void* d_ws, size_t ws_size,
                              hipStream_t stream) {
    const float* x   = (const float*)d_in[0];
    const float* h0  = (const float*)d_in[1];
    const float* Wih = (const float*)d_in[2];
    const float* bih = (const float*)d_in[3];
    const float* Whh = (const float*)d_in[4];
    const float* bhh = (const float*)d_in[5];
    float* outp  = (float*)d_out;
    int*   flags = (int*)d_ws;   // NWG per-WG step flags (2 KB)

    (void)in_sizes; (void)n_in; (void)ws_size; (void)out_size;

    // zero the per-WG flags every launch (stream-ordered, capture-safe)
    hipMemsetAsync(d_ws, 0, NWG * sizeof(int), stream);

    gru_scan_kernel<<<dim3(NWG), dim3(NTHR), LDS_BYTES, stream>>>(
        x, h0, Wih, bih, Whh, bhh, outp, flags);
}